// Round 1
// baseline (401.000 us; speedup 1.0000x reference)
//
#include <hip/hip_runtime.h>
#include <hip/hip_bf16.h>

typedef __attribute__((ext_vector_type(8))) short bf16x8;
typedef __attribute__((ext_vector_type(4))) float f32x4;
typedef unsigned short ushort_t;

__device__ __forceinline__ void gload16(const void* g, void* l) {
  __builtin_amdgcn_global_load_lds(
      (const __attribute__((address_space(1))) void*)g,
      (__attribute__((address_space(3))) void*)l, 16, 0, 0);
}

// ---------------- K1: styles[n][ci] = w[n] . affine_w[ci] * (1/sqrt(512)) + affine_b[ci]
__global__ void k_styles(const float* __restrict__ w, const float* __restrict__ aw,
                         const float* __restrict__ ab, float* __restrict__ styles) {
  int n = blockIdx.x;        // 8
  int ci = threadIdx.x;      // 256
  const float4* wr = (const float4*)(w + n * 512);
  const float4* ar = (const float4*)(aw + (size_t)ci * 512);
  float s = 0.f;
  #pragma unroll 4
  for (int j = 0; j < 128; j++) {
    float4 a = ar[j], b = wr[j];
    s += a.x * b.x + a.y * b.y + a.z * b.z + a.w * b.w;
  }
  styles[n * 256 + ci] = s * 0.044194173824159216f + ab[ci];
}

// ---------------- K2: modulate + demodulate, write bf16 weights
// layout: wwg[n][kh][cc=ci/32][kw][co 256][ci%32]   (ci-contiguous 64B rows)
__global__ void k_modw(const float* __restrict__ weight, const float* __restrict__ styles,
                       ushort_t* __restrict__ wwg) {
  int id = blockIdx.x * 4 + (threadIdx.x >> 6);  // 2048 waves: (n, co)
  int l = threadIdx.x & 63;
  int n = id >> 8, co = id & 255;
  const float* wrow = weight + (size_t)co * 2304;   // [ci][kh][kw]
  const float* srow = styles + n * 256;
  float mv[36];
  float sum = 0.f;
  #pragma unroll
  for (int tap = 0; tap < 9; tap++) {
    #pragma unroll
    for (int cg = 0; cg < 4; cg++) {
      int ci = cg * 64 + l;
      float v = wrow[ci * 9 + tap] * srow[ci];
      mv[tap * 4 + cg] = v;
      sum += v * v;
    }
  }
  #pragma unroll
  for (int off = 32; off; off >>= 1) sum += __shfl_xor(sum, off, 64);
  float d = rsqrtf(sum + 1e-8f);
  #pragma unroll
  for (int tap = 0; tap < 9; tap++) {
    int kh = tap / 3, kw = tap % 3;   // compile-time (unrolled)
    #pragma unroll
    for (int cg = 0; cg < 4; cg++) {
      int ci = cg * 64 + l;
      float v = mv[tap * 4 + cg] * d;
      __hip_bfloat16 hb = __float2bfloat16(v);
      size_t oidx = ((((size_t)((n * 3 + kh) * 8) + (ci >> 5)) * 3 + kw) * 256 + co) * 32 + (ci & 31);
      wwg[oidx] = *reinterpret_cast<ushort_t*>(&hb);
    }
  }
}

// ---------------- K3: x NCHW f32 -> Xt NHWC bf16
__global__ void k_transpose(const float* __restrict__ x, ushort_t* __restrict__ xt) {
  int n = blockIdx.z, h = blockIdx.y;
  int wt = blockIdx.x & 1, ct = blockIdx.x >> 1;   // gridDim.x = 8
  int w0 = wt * 64, ci0 = ct * 64;
  __shared__ float tile[64][65];
  int t = threadIdx.x;
  {
    int ci_l = t >> 2, wq = (t & 3) * 16;
    const float* src = x + (((size_t)(n * 256 + ci0 + ci_l) * 128 + h) * 128 + w0 + wq);
    #pragma unroll
    for (int j = 0; j < 4; j++) {
      float4 v = ((const float4*)src)[j];
      tile[ci_l][wq + j * 4 + 0] = v.x;
      tile[ci_l][wq + j * 4 + 1] = v.y;
      tile[ci_l][wq + j * 4 + 2] = v.z;
      tile[ci_l][wq + j * 4 + 3] = v.w;
    }
  }
  __syncthreads();
  {
    int w_l = t >> 2, cq = (t & 3) * 16;
    union { ushort_t u[16]; uint4 v[2]; } pk;
    #pragma unroll
    for (int j = 0; j < 16; j++) {
      __hip_bfloat16 hb = __float2bfloat16(tile[cq + j][w_l]);
      pk.u[j] = *reinterpret_cast<ushort_t*>(&hb);
    }
    size_t off = ((size_t)((n * 128 + h) * 128) + w0 + w_l) * 256 + ci0 + cq;
    uint4* dst = (uint4*)(xt + off);
    dst[0] = pk.v[0];
    dst[1] = pk.v[1];
  }
}

// ---------------- K4: implicit-GEMM conv + bias + lrelu*sqrt2 + sigmoid
// block: (cb co-half, h-pair, n); 4 waves = 2(co)x2(row); wave tile 64co x 128w
// LDS: A [kw3][co128][ci32] = 24576B ; B 2 row-bufs [132][ci32] = 2*8448B
__global__ __launch_bounds__(256, 2) void k_conv(
    const ushort_t* __restrict__ xt, const ushort_t* __restrict__ wwg,
    const float* __restrict__ bias, float* __restrict__ out) {
  __shared__ __align__(16) char smem[24576 + 2 * 8448];
  char* sA = smem;
  char* sB = smem + 24576;

  const int cb = blockIdx.x;       // 0..1
  const int h0 = blockIdx.y * 2;   // 0..126
  const int n  = blockIdx.z;       // 0..7

  const int t = threadIdx.x;
  const int wave = t >> 6;
  const int l = t & 63;
  const int wr = wave >> 1, wc = wave & 1;
  const int c = l & 15, kg = l >> 4;

  f32x4 acc[4][8];
  #pragma unroll
  for (int i = 0; i < 4; i++)
    #pragma unroll
    for (int j = 0; j < 8; j++)
      acc[i][j] = (f32x4){0.f, 0.f, 0.f, 0.f};

  // zero w-border rows (row 0 => w=-1, rows 129..131 => w>=128) in both buffers
  if (t < 64) {
    int buf = t >> 5;
    int r = t & 31;
    if (r < 16) {
      int rowsel = r >> 2;
      int row = (rowsel == 0) ? 0 : (128 + rowsel);   // 0,129,130,131
      *(f32x4*)(sB + buf * 8448 + row * 64 + (r & 3) * 16) = (f32x4){0.f, 0.f, 0.f, 0.f};
    }
  }

  const long long xtN = (long long)n * (128LL * 128 * 256);

  for (int kh = 0; kh < 3; kh++) {
    const int hsrc_w = h0 + wc + kh - 1;                 // this wave's source row
    const bool valid = (hsrc_w >= 0) && (hsrc_w < 128);
    const char* gAkh = (const char*)(wwg + ((size_t)(n * 3 + kh)) * (8 * 3 * 256 * 32));
    for (int cc = 0; cc < 8; cc++) {
      __syncthreads();   // previous compute done; borders visible on iter 0
      // ---- stage A: 1536 granules, 6 iters
      const char* gA = gAkh + (size_t)cc * (3 * 256 * 32 * 2);
      #pragma unroll
      for (int i = 0; i < 6; i++) {
        int G = i * 256 + t;
        int kw = G >> 9, r = G & 511;
        const char* gp = gA + kw * 16384 + cb * 8192 + r * 16;
        char* lp = sA + (i * 256 + wave * 64) * 16;      // wave-uniform base
        gload16(gp, lp);
      }
      // ---- stage B: 2 bufs x 512 granules, 4 iters
      #pragma unroll
      for (int i = 0; i < 4; i++) {
        int G = i * 256 + t;
        int r = G & 511;
        int w = r >> 2, gg = r & 3;
        int buf = G >> 9;
        int hsrc = h0 + kh - 1 + buf;
        const char* gp = (const char*)xt +
            ((xtN + (long long)(hsrc * 128 + w) * 256 + cc * 32 + gg * 8) * 2);
        int B0 = i * 256 + wave * 64;
        char* lp = sB + (B0 >> 9) * 8448 + 64 + (B0 & 511) * 16;  // wave-uniform
        gload16(gp, lp);
      }
      asm volatile("s_waitcnt vmcnt(0)" ::: "memory");
      __syncthreads();
      // ---- compute
      if (valid) {
        const char* bBase = sB + wc * 8448;
        #pragma unroll
        for (int s = 0; s < 3; s++) {
          bf16x8 af[4];
          #pragma unroll
          for (int mi = 0; mi < 4; mi++)
            af[mi] = *(const bf16x8*)(sA + s * 8192 + (wr * 64 + mi * 16 + c) * 64 + kg * 16);
          bf16x8 bfr[8];
          #pragma unroll
          for (int ni = 0; ni < 8; ni++)
            bfr[ni] = *(const bf16x8*)(bBase + (ni * 16 + c + s) * 64 + kg * 16);
          #pragma unroll
          for (int mi = 0; mi < 4; mi++)
            #pragma unroll
            for (int ni = 0; ni < 8; ni++)
              acc[mi][ni] = __builtin_amdgcn_mfma_f32_16x16x32_bf16(af[mi], bfr[ni], acc[mi][ni], 0, 0, 0);
        }
      }
    }
  }

  // ---- epilogue: bias + lrelu*sqrt2 + sigmoid, write f32 NCHW
  const int hrow = h0 + wc;
  #pragma unroll
  for (int mi = 0; mi < 4; mi++) {
    #pragma unroll
    for (int r = 0; r < 4; r++) {
      int co = cb * 128 + wr * 64 + mi * 16 + kg * 4 + r;
      float bval = bias[co];
      #pragma unroll
      for (int ni = 0; ni < 8; ni++) {
        float v = acc[mi][ni][r] + bval;
        v = (v >= 0.f ? v : 0.2f * v) * 1.41421356237f;
        float o = 1.f / (1.f + __expf(-v));
        out[(((size_t)(n * 256 + co)) * 128 + hrow) * 128 + ni * 16 + c] = o;
      }
    }
  }
}

extern "C" void kernel_launch(void* const* d_in, const int* in_sizes, int n_in,
                              void* d_out, int out_size, void* d_ws, size_t ws_size,
                              hipStream_t stream) {
  const float* x      = (const float*)d_in[0];
  const float* w      = (const float*)d_in[1];
  const float* aw     = (const float*)d_in[2];
  const float* ab     = (const float*)d_in[3];
  const float* weight = (const float*)d_in[4];
  const float* bias   = (const float*)d_in[5];
  float* out = (float*)d_out;

  char* ws = (char*)d_ws;
  float*    styles = (float*)ws;                                  // 8 KB
  ushort_t* wwg    = (ushort_t*)(ws + 8192);                      // 9,437,184 B
  ushort_t* xt     = (ushort_t*)(ws + 8192 + 9437184);            // 67,108,864 B (+1MB slack for h-border OOB)

  k_styles<<<8, 256, 0, stream>>>(w, aw, ab, styles);
  k_modw<<<512, 256, 0, stream>>>(weight, styles, wwg);
  k_transpose<<<dim3(8, 128, 8), 256, 0, stream>>>(x, xt);
  k_conv<<<dim3(2, 64, 8), 256, 0, stream>>>(xt, wwg, bias, out);
}

// Round 2
// 377.172 us; speedup vs baseline: 1.0632x; 1.0632x over previous
//
#include <hip/hip_runtime.h>
#include <hip/hip_bf16.h>

typedef __attribute__((ext_vector_type(8))) short bf16x8;
typedef __attribute__((ext_vector_type(4))) float f32x4;
typedef unsigned short ushort_t;

__device__ __forceinline__ void gload16(const void* g, void* l) {
  __builtin_amdgcn_global_load_lds(
      (const __attribute__((address_space(1))) void*)g,
      (__attribute__((address_space(3))) void*)l, 16, 0, 0);
}

// ---------------- K1: styles[n][ci] = w[n] . affine_w[ci] * (1/sqrt(512)) + affine_b[ci]
// one wave per (n, ci): fully coalesced 32B/lane reads, shfl reduce.
__global__ void k_styles(const float* __restrict__ w, const float* __restrict__ aw,
                         const float* __restrict__ ab, float* __restrict__ styles) {
  int wave = threadIdx.x >> 6, l = threadIdx.x & 63;
  int id = blockIdx.x * 4 + wave;   // 0..2047
  int n = id >> 8, ci = id & 255;
  const float4* ar = (const float4*)(aw + (size_t)ci * 512);
  const float4* wr = (const float4*)(w + n * 512);
  float s = 0.f;
  #pragma unroll
  for (int j = 0; j < 2; j++) {
    float4 a = ar[l * 2 + j], b = wr[l * 2 + j];
    s += a.x * b.x + a.y * b.y + a.z * b.z + a.w * b.w;
  }
  #pragma unroll
  for (int off = 32; off; off >>= 1) s += __shfl_xor(s, off, 64);
  if (l == 0) styles[n * 256 + ci] = s * 0.044194173824159216f + ab[ci];
}

// ---------------- K2: modulate + demodulate, write bf16 weights
// coalesced flat read of the 2304-float row -> per-wave LDS buffer -> ordered writes.
// layout: wwg[n][kh][cc=ci/32][kw][co 256][ci%32]   (ci-contiguous 64B rows)
__global__ __launch_bounds__(256) void k_modw(const float* __restrict__ weight,
                                              const float* __restrict__ styles,
                                              ushort_t* __restrict__ wwg) {
  __shared__ float wl[4][2304];
  __shared__ float s_sty[256];
  int wave = threadIdx.x >> 6, l = threadIdx.x & 63;
  int id = blockIdx.x * 4 + wave;  // (n, co); n uniform within block
  int n = id >> 8, co = id & 255;
  s_sty[threadIdx.x] = styles[(size_t)n * 256 + threadIdx.x];
  __syncthreads();
  const float* wrow = weight + (size_t)co * 2304;   // flat [ci][kh][kw]
  float sq = 0.f;
  #pragma unroll
  for (int i = 0; i < 36; i++) {
    int idx = i * 64 + l;
    float v = wrow[idx] * s_sty[idx / 9];
    sq += v * v;
    wl[wave][idx] = v;
  }
  #pragma unroll
  for (int off = 32; off; off >>= 1) sq += __shfl_xor(sq, off, 64);
  float d = rsqrtf(sq + 1e-8f);
  #pragma unroll
  for (int tap = 0; tap < 9; tap++) {
    int kh = tap / 3, kw = tap % 3;
    #pragma unroll
    for (int cg = 0; cg < 4; cg++) {
      int ci = cg * 64 + l;
      float v = wl[wave][ci * 9 + tap] * d;
      __hip_bfloat16 hb = __float2bfloat16(v);
      size_t oidx = ((((size_t)((n * 3 + kh) * 8) + (ci >> 5)) * 3 + kw) * 256 + co) * 32 + (ci & 31);
      wwg[oidx] = *reinterpret_cast<ushort_t*>(&hb);
    }
  }
}

// ---------------- K3: x NCHW f32 -> Xt NHWC bf16
__global__ void k_transpose(const float* __restrict__ x, ushort_t* __restrict__ xt) {
  int n = blockIdx.z, h = blockIdx.y;
  int wt = blockIdx.x & 1, ct = blockIdx.x >> 1;   // gridDim.x = 8
  int w0 = wt * 64, ci0 = ct * 64;
  __shared__ float tile[64][68];                   // pad 4: 16B-aligned rows
  int t = threadIdx.x;
  {
    int ci_l = t >> 2, wq = (t & 3) * 16;
    const float* src = x + (((size_t)(n * 256 + ci0 + ci_l) * 128 + h) * 128 + w0 + wq);
    #pragma unroll
    for (int j = 0; j < 4; j++)
      *(float4*)&tile[ci_l][wq + j * 4] = ((const float4*)src)[j];
  }
  __syncthreads();
  {
    int w_l = t >> 2, cq = (t & 3) * 16;
    union { ushort_t u[16]; uint4 v[2]; } pk;
    #pragma unroll
    for (int j = 0; j < 16; j++) {
      __hip_bfloat16 hb = __float2bfloat16(tile[cq + j][w_l]);
      pk.u[j] = *reinterpret_cast<ushort_t*>(&hb);
    }
    size_t off = ((size_t)((n * 128 + h) * 128) + w0 + w_l) * 256 + ci0 + cq;
    uint4* dst = (uint4*)(xt + off);
    dst[0] = pk.v[0];
    dst[1] = pk.v[1];
  }
}

// ---------------- K4: implicit-GEMM conv + bias + lrelu*sqrt2 + sigmoid
// block: (cb co-half, h-pair, n); 4 waves = 2(co)x2(row); wave tile 64co x 128w
// XCD-aware mapping: n = bid & 7 (one n per XCD), h-contiguous within XCD.
// LDS: A [kw3][co128][ci32] = 24576B ; B 2 row-bufs [132][ci32] = 2*8448B
__global__ __launch_bounds__(256, 2) void k_conv(
    const ushort_t* __restrict__ xt, const ushort_t* __restrict__ wwg,
    const float* __restrict__ bias, float* __restrict__ out) {
  __shared__ __align__(16) char smem[24576 + 2 * 8448];
  char* sA = smem;
  char* sB = smem + 24576;

  const int bid = blockIdx.x;
  const int n  = bid & 7;          // == XCD (round-robin dispatch)
  const int r  = bid >> 3;         // 0..127, increasing in time per XCD
  const int cb = r & 1;
  const int h0 = (r >> 1) * 2;     // adjacent h-blocks adjacent in time -> L2 row reuse

  const int t = threadIdx.x;
  const int wave = t >> 6;
  const int l = t & 63;
  const int wr = wave >> 1, wc = wave & 1;
  const int c = l & 15, kg = l >> 4;

  f32x4 acc[4][8];
  #pragma unroll
  for (int i = 0; i < 4; i++)
    #pragma unroll
    for (int j = 0; j < 8; j++)
      acc[i][j] = (f32x4){0.f, 0.f, 0.f, 0.f};

  // zero w-border rows (row 0 => w=-1, rows 129..131 => w>=128) in both buffers
  if (t < 64) {
    int buf = t >> 5;
    int rr = t & 31;
    if (rr < 16) {
      int rowsel = rr >> 2;
      int row = (rowsel == 0) ? 0 : (128 + rowsel);   // 0,129,130,131
      *(f32x4*)(sB + buf * 8448 + row * 64 + (rr & 3) * 16) = (f32x4){0.f, 0.f, 0.f, 0.f};
    }
  }

  const long long xtN = (long long)n * (128LL * 128 * 256);

  for (int kh = 0; kh < 3; kh++) {
    const int hsrc_w = h0 + wc + kh - 1;                 // this wave's source row
    const bool valid = (hsrc_w >= 0) && (hsrc_w < 128);
    const char* gAkh = (const char*)(wwg + ((size_t)(n * 3 + kh)) * (8 * 3 * 256 * 32));
    for (int cc = 0; cc < 8; cc++) {
      __syncthreads();   // previous compute done; borders visible on iter 0
      // ---- stage A: 1536 granules, 6 iters
      const char* gA = gAkh + (size_t)cc * (3 * 256 * 32 * 2);
      #pragma unroll
      for (int i = 0; i < 6; i++) {
        int G = i * 256 + t;
        int kw = G >> 9, rr = G & 511;
        const char* gp = gA + kw * 16384 + cb * 8192 + rr * 16;
        char* lp = sA + (i * 256 + wave * 64) * 16;      // wave-uniform base
        gload16(gp, lp);
      }
      // ---- stage B: 2 bufs x 512 granules, 4 iters
      #pragma unroll
      for (int i = 0; i < 4; i++) {
        int G = i * 256 + t;
        int rr = G & 511;
        int w = rr >> 2, gg = rr & 3;
        int buf = G >> 9;
        int hsrc = h0 + kh - 1 + buf;
        const char* gp = (const char*)xt +
            ((xtN + (long long)(hsrc * 128 + w) * 256 + cc * 32 + gg * 8) * 2);
        int B0 = i * 256 + wave * 64;
        char* lp = sB + (B0 >> 9) * 8448 + 64 + (B0 & 511) * 16;  // wave-uniform
        gload16(gp, lp);
      }
      asm volatile("s_waitcnt vmcnt(0)" ::: "memory");
      __syncthreads();
      // ---- compute
      if (valid) {
        const char* bBase = sB + wc * 8448;
        #pragma unroll
        for (int s = 0; s < 3; s++) {
          bf16x8 af[4];
          #pragma unroll
          for (int mi = 0; mi < 4; mi++)
            af[mi] = *(const bf16x8*)(sA + s * 8192 + (wr * 64 + mi * 16 + c) * 64 + kg * 16);
          bf16x8 bfr[8];
          #pragma unroll
          for (int ni = 0; ni < 8; ni++)
            bfr[ni] = *(const bf16x8*)(bBase + (ni * 16 + c + s) * 64 + kg * 16);
          #pragma unroll
          for (int mi = 0; mi < 4; mi++)
            #pragma unroll
            for (int ni = 0; ni < 8; ni++)
              acc[mi][ni] = __builtin_amdgcn_mfma_f32_16x16x32_bf16(af[mi], bfr[ni], acc[mi][ni], 0, 0, 0);
        }
      }
    }
  }

  // ---- epilogue: bias + lrelu*sqrt2 + sigmoid, write f32 NCHW
  const int hrow = h0 + wc;
  #pragma unroll
  for (int mi = 0; mi < 4; mi++) {
    #pragma unroll
    for (int rr = 0; rr < 4; rr++) {
      int co = cb * 128 + wr * 64 + mi * 16 + kg * 4 + rr;
      float bval = bias[co];
      #pragma unroll
      for (int ni = 0; ni < 8; ni++) {
        float v = acc[mi][ni][rr] + bval;
        v = (v >= 0.f ? v : 0.2f * v) * 1.41421356237f;
        float o = 1.f / (1.f + __expf(-v));
        out[(((size_t)(n * 256 + co)) * 128 + hrow) * 128 + ni * 16 + c] = o;
      }
    }
  }
}

extern "C" void kernel_launch(void* const* d_in, const int* in_sizes, int n_in,
                              void* d_out, int out_size, void* d_ws, size_t ws_size,
                              hipStream_t stream) {
  const float* x      = (const float*)d_in[0];
  const float* w      = (const float*)d_in[1];
  const float* aw     = (const float*)d_in[2];
  const float* ab     = (const float*)d_in[3];
  const float* weight = (const float*)d_in[4];
  const float* bias   = (const float*)d_in[5];
  float* out = (float*)d_out;

  char* ws = (char*)d_ws;
  float*    styles = (float*)ws;                                  // 8 KB
  ushort_t* wwg    = (ushort_t*)(ws + 8192);                      // 9,437,184 B
  ushort_t* xt     = (ushort_t*)(ws + 8192 + 9437184);            // 67,108,864 B (+slack for h-border OOB)

  k_styles<<<512, 256, 0, stream>>>(w, aw, ab, styles);
  k_modw<<<512, 256, 0, stream>>>(weight, styles, wwg);
  k_transpose<<<dim3(8, 128, 8), 256, 0, stream>>>(x, xt);
  k_conv<<<1024, 256, 0, stream>>>(xt, wwg, bias, out);
}